// Round 5
// baseline (228.322 us; speedup 1.0000x reference)
//
#include <hip/hip_runtime.h>
#include <hip/hip_bf16.h>

// ReBASED attention R5: occupancy-first rebuild.
// BQ=64 per block (4 waves x 16 qrows each, every wave active every kt),
// paired q-tiles (j,31-j) -> uniform 33 kt/block, grid=1024 (4 blocks/CU,
// 16 waves/CU). QK via 16x16xK32 S^T (A=K, B=Q-in-regs); its C-layout equals
// the A-layout of 16x16xK16 PV -> P stays in registers, NO shfl, no P-LDS.
// Double-buffered K/V staging + register prefetch. XCD swizzle: all 16 blocks
// of a head land on one XCD -> K/V tiles are L2-resident.

#define SEQ 2048
#define HD  64
#define BK  64
#define LK  72   // Ks row stride in shorts (144 B, b128-aligned)
#define LV  76   // Vst row stride in shorts (152 B, b64-aligned)

typedef __attribute__((ext_vector_type(8))) short bf16x8;
typedef __attribute__((ext_vector_type(4))) short bf16x4;
typedef __attribute__((ext_vector_type(4))) float f32x4;

__device__ inline unsigned packbf(float a, float b) {
    __hip_bfloat162 hh = __float22bfloat162_rn(make_float2(a, b));  // a->lo, b->hi
    union { __hip_bfloat162 h2; unsigned u; } cv; cv.h2 = hh; return cv.u;
}

__global__ __launch_bounds__(256, 4)
void rebased_r5_kernel(const float* __restrict__ qg,
                       const float* __restrict__ kg,
                       const float* __restrict__ vg,
                       float* __restrict__ og) {
    __shared__ __align__(16) unsigned short Ks[2][BK][LK];   // K[kcol][d] bf16
    __shared__ __align__(16) unsigned short Vst[2][HD][LV];  // V^T[d][kcol] bf16

    const int t    = threadIdx.x;
    const int lane = t & 63;
    const int w    = t >> 6;        // wave -> qrows [w*16, w*16+16) of the 64-tile
    const int li   = lane & 15;
    const int qd   = lane >> 4;     // quad
    // XCD swizzle: ids stride-8 share an XCD -> co-locate each head's blocks.
    const int id   = blockIdx.x;
    const int xm   = id & 7;
    const int qq   = id >> 3;            // 0..127
    const int pj   = qq & 15;            // pair index 0..15
    const int head = xm + 8 * (qq >> 4); // 0..63
    const size_t base = (size_t)head * SEQ * HD;
    const int d4g = t & 15, rp = t >> 4;

    #pragma unroll
    for (int seg = 0; seg < 2; ++seg) {
        const int qt = seg ? pj : (31 - pj);   // big tile first
        const int ktmax = qt;                  // kt = 0..qt inclusive
        const int qrow = qt * 64 + w * 16 + li;

        // ---- Q fragment -> registers (B-operand of 16x16xK32, scale folded) ----
        bf16x8 qf[2];
        {
            const float* qp = qg + base + (size_t)qrow * HD + qd * 8;
            #pragma unroll
            for (int ks = 0; ks < 2; ++ks) {
                float4 a = *(const float4*)(qp + ks * 32);
                float4 b = *(const float4*)(qp + ks * 32 + 4);
                union { unsigned u[4]; bf16x8 v; } cv;
                cv.u[0] = packbf(a.x * 0.125f, a.y * 0.125f);
                cv.u[1] = packbf(a.z * 0.125f, a.w * 0.125f);
                cv.u[2] = packbf(b.x * 0.125f, b.y * 0.125f);
                cv.u[3] = packbf(b.z * 0.125f, b.w * 0.125f);
                qf[ks] = cv.v;
            }
        }

        // ---- load kt=0 K/V into registers ----
        float4 kreg[4], vreg[4];
        {
            const float4* ksrc = (const float4*)(kg + base);
            const float4* vsrc = (const float4*)(vg + base);
            #pragma unroll
            for (int l = 0; l < 4; ++l) kreg[l] = ksrc[t + l * 256];
            #pragma unroll
            for (int p = 0; p < 2; ++p) {
                int r0 = p * 32 + rp * 2;
                vreg[2 * p]     = vsrc[r0 * 16 + d4g];
                vreg[2 * p + 1] = vsrc[(r0 + 1) * 16 + d4g];
            }
        }
        __syncthreads();   // prior segment's LDS reads complete

        // ---- write kt=0 into buffer 0 ----
        #pragma unroll
        for (int l = 0; l < 4; ++l) {
            int f = t + l * 256, row = f >> 4, d4 = (f & 15) << 2;
            unsigned* dst = (unsigned*)&Ks[0][row][d4];
            dst[0] = packbf(kreg[l].x, kreg[l].y);
            dst[1] = packbf(kreg[l].z, kreg[l].w);
        }
        #pragma unroll
        for (int p = 0; p < 2; ++p) {
            int r0 = p * 32 + rp * 2;
            float a0[4] = {vreg[2*p].x, vreg[2*p].y, vreg[2*p].z, vreg[2*p].w};
            float a1[4] = {vreg[2*p+1].x, vreg[2*p+1].y, vreg[2*p+1].z, vreg[2*p+1].w};
            #pragma unroll
            for (int j = 0; j < 4; ++j)
                *(unsigned*)&Vst[0][d4g * 4 + j][r0] = packbf(a0[j], a1[j]);
        }
        __syncthreads();

        f32x4 oacc[4];
        #pragma unroll
        for (int nd = 0; nd < 4; ++nd) oacc[nd] = (f32x4){0.f, 0.f, 0.f, 0.f};
        float zpart = 0.f;

        for (int kt = 0; kt <= ktmax; ++kt) {
            const int cur = kt & 1;

            // ---- prefetch kt+1 K/V into registers ----
            if (kt < ktmax) {
                const float4* ksrc = (const float4*)(kg + base + (size_t)(kt + 1) * BK * HD);
                const float4* vsrc = (const float4*)(vg + base + (size_t)(kt + 1) * BK * HD);
                #pragma unroll
                for (int l = 0; l < 4; ++l) kreg[l] = ksrc[t + l * 256];
                #pragma unroll
                for (int p = 0; p < 2; ++p) {
                    int r0 = p * 32 + rp * 2;
                    vreg[2 * p]     = vsrc[r0 * 16 + d4g];
                    vreg[2 * p + 1] = vsrc[(r0 + 1) * 16 + d4g];
                }
            }

            // ---- S^T = K·Q^T : 4 kcol-tiles x K-depth 64 (2 steps) ----
            f32x4 stt[4];
            #pragma unroll
            for (int nk = 0; nk < 4; ++nk) stt[nk] = (f32x4){0.f, 0.f, 0.f, 0.f};
            #pragma unroll
            for (int ks = 0; ks < 2; ++ks) {
                const int kb = ks * 32 + qd * 8;
                bf16x8 kf[4];
                #pragma unroll
                for (int nk = 0; nk < 4; ++nk)
                    kf[nk] = *(const bf16x8*)&Ks[cur][nk * 16 + li][kb];
                #pragma unroll
                for (int nk = 0; nk < 4; ++nk)
                    stt[nk] = __builtin_amdgcn_mfma_f32_16x16x32_bf16(
                        kf[nk], qf[ks], stt[nk], 0, 0, 0);
            }

            // ---- square + causal mask (diagonal kt only) + z + pack ----
            unsigned pk[4][2];
            const bool needmask = (kt == qt);
            #pragma unroll
            for (int nk = 0; nk < 4; ++nk) {
                const int kcb = kt * 64 + nk * 16 + qd * 4;
                float p[4];
                #pragma unroll
                for (int r = 0; r < 4; ++r) {
                    float s = stt[nk][r];
                    float pv = s * s;
                    if (needmask && (kcb + r > qrow)) pv = 0.f;
                    p[r] = pv;
                }
                zpart += (p[0] + p[1]) + (p[2] + p[3]);
                pk[nk][0] = packbf(p[0], p[1]);
                pk[nk][1] = packbf(p[2], p[3]);
            }

            // ---- O += P·V : A=P in regs (C==A layout identity), B=V^T from LDS ----
            #pragma unroll
            for (int ks16 = 0; ks16 < 4; ++ks16) {
                union { unsigned u[2]; bf16x4 v; } av;
                av.u[0] = pk[ks16][0]; av.u[1] = pk[ks16][1];
                #pragma unroll
                for (int nd = 0; nd < 4; ++nd) {
                    bf16x4 vf = *(const bf16x4*)&Vst[cur][nd * 16 + li][ks16 * 16 + qd * 4];
                    oacc[nd] = __builtin_amdgcn_mfma_f32_16x16x16bf16_1k(
                        av.v, vf, oacc[nd], 0, 0, 0);
                }
            }

            // ---- write prefetched kt+1 into the other buffer ----
            if (kt < ktmax) {
                const int nb = cur ^ 1;
                #pragma unroll
                for (int l = 0; l < 4; ++l) {
                    int f = t + l * 256, row = f >> 4, d4 = (f & 15) << 2;
                    unsigned* dst = (unsigned*)&Ks[nb][row][d4];
                    dst[0] = packbf(kreg[l].x, kreg[l].y);
                    dst[1] = packbf(kreg[l].z, kreg[l].w);
                }
                #pragma unroll
                for (int p = 0; p < 2; ++p) {
                    int r0 = p * 32 + rp * 2;
                    float a0[4] = {vreg[2*p].x, vreg[2*p].y, vreg[2*p].z, vreg[2*p].w};
                    float a1[4] = {vreg[2*p+1].x, vreg[2*p+1].y, vreg[2*p+1].z, vreg[2*p+1].w};
                    #pragma unroll
                    for (int j = 0; j < 4; ++j)
                        *(unsigned*)&Vst[nb][d4g * 4 + j][r0] = packbf(a0[j], a1[j]);
                }
            }
            __syncthreads();
        }

        // ---- epilogue: z reduce over quads + divide + store ----
        float zf = zpart;
        zf += __shfl_xor(zf, 16, 64);
        zf += __shfl_xor(zf, 32, 64);            // lane holds z for qrow w*16+li
        float zinv = 1.f / (zf + 1e-6f);
        float* odst = og + base + (size_t)(qt * 64) * HD;
        #pragma unroll
        for (int r = 0; r < 4; ++r) {
            float inv = __shfl(zinv, qd * 4 + r, 64);
            int rowl = w * 16 + qd * 4 + r;
            #pragma unroll
            for (int nd = 0; nd < 4; ++nd)
                odst[(size_t)rowl * HD + nd * 16 + li] = oacc[nd][r] * inv;
        }
    }
}

extern "C" void kernel_launch(void* const* d_in, const int* in_sizes, int n_in,
                              void* d_out, int out_size, void* d_ws, size_t ws_size,
                              hipStream_t stream) {
    const float* q = (const float*)d_in[0];
    const float* k = (const float*)d_in[1];
    const float* v = (const float*)d_in[2];
    float* out = (float*)d_out;

    dim3 grid(1024);   // 16 uniform pairs x 64 heads, XCD-swizzled -> 4 blocks/CU
    dim3 block(256);
    rebased_r5_kernel<<<grid, block, 0, stream>>>(q, k, v, out);
}